// Round 2
// baseline (305.635 us; speedup 1.0000x reference)
//
#include <hip/hip_runtime.h>
#include <hip/hip_bf16.h>

#define NHEAD 4
#define FIN   768
#define FOUT  64
#define BSZ   4
#define NSEQ  2048

// ---------------------------------------------------------------------------
// Kernel A: h_prime[b,h,n,o] = sum_f h[b,n,f] * w[h,f,o]   (fp32)
// plus attn_src[b,h,n] = sum_o tanh(h_prime)*a_src[h,o], same for dst.
// Block: 256 threads = (head = tid>>6 -> one wave per head, o = tid&63),
// 4 rows of h per block staged in LDS.
// ---------------------------------------------------------------------------
__global__ __launch_bounds__(256, 2) void k_hprime(
    const float* __restrict__ h, const float* __restrict__ w,
    const float* __restrict__ a_src, const float* __restrict__ a_dst,
    float* __restrict__ hp, float* __restrict__ srcv, float* __restrict__ dstv)
{
  const int blk = blockIdx.x;               // BSZ*NSEQ/4 blocks
  const int b   = blk / (NSEQ/4);
  const int r0  = (blk % (NSEQ/4)) * 4;
  const int tid = threadIdx.x;
  const int hh  = tid >> 6;                 // head (each wave = one head)
  const int oo  = tid & 63;                 // output feature

  __shared__ __align__(16) float hsh[4][FIN];
  const float* hrow = h + ((size_t)b*NSEQ + r0)*FIN;
  const float4* hrow4 = (const float4*)hrow;       // 768%4==0, base 16B aligned
  float4* hsh4 = (float4*)(&hsh[0][0]);
  #pragma unroll
  for (int idx = tid; idx < 4*FIN/4; idx += 256) hsh4[idx] = hrow4[idx];
  __syncthreads();

  float a0=0.f, a1=0.f, a2=0.f, a3=0.f;
  const float* wp = w + ((size_t)hh*FIN)*FOUT + oo;
  #pragma unroll 8
  for (int f = 0; f < FIN; ++f){
    float wv = wp[(size_t)f*FOUT];
    a0 = fmaf(hsh[0][f], wv, a0);
    a1 = fmaf(hsh[1][f], wv, a1);
    a2 = fmaf(hsh[2][f], wv, a2);
    a3 = fmaf(hsh[3][f], wv, a3);
  }

  const float as = a_src[tid];   // a_src[h,o,1] flat == tid
  const float ad = a_dst[tid];
  const int bh = b*NHEAD + hh;
  float accs[4] = {a0,a1,a2,a3};
  #pragma unroll
  for (int r = 0; r < 4; ++r){
    float v = accs[r];
    hp[((size_t)bh*NSEQ + (r0+r))*FOUT + oo] = v;
    float t  = tanhf(v);
    float ps = t*as, pd = t*ad;
    #pragma unroll
    for (int off = 32; off > 0; off >>= 1){   // wave64 reduce (one head/wave)
      ps += __shfl_down(ps, off, 64);
      pd += __shfl_down(pd, off, 64);
    }
    if (oo == 0){
      srcv[(size_t)bh*NSEQ + r0 + r] = ps;
      dstv[(size_t)bh*NSEQ + r0 + r] = pd;
    }
  }
}

// ---------------------------------------------------------------------------
// Kernel A2: dmax[bh] = max_j dstv[bh, j]
// ---------------------------------------------------------------------------
__global__ __launch_bounds__(256) void k_dmax(
    const float* __restrict__ dstv, float* __restrict__ dmax)
{
  const int bh = blockIdx.x;
  const int tid = threadIdx.x;
  float m = -1e30f;
  for (int j = tid; j < NSEQ; j += 256) m = fmaxf(m, dstv[(size_t)bh*NSEQ + j]);
  #pragma unroll
  for (int off = 32; off > 0; off >>= 1) m = fmaxf(m, __shfl_down(m, off, 64));
  __shared__ float sm[4];
  if ((tid & 63) == 0) sm[tid >> 6] = m;
  __syncthreads();
  if (tid == 0) dmax[bh] = fmaxf(fmaxf(sm[0],sm[1]), fmaxf(sm[2],sm[3]));
}

// ---------------------------------------------------------------------------
// Kernel B: per (b,h), 64-row output tile. Exact softmax in one pass:
//   m_i = lrelu(s_i + dmax)  (lrelu monotone => exact row max)
//   p_ij = exp(lrelu(s_i + d_j) - m_i);  l_i = sum_j p_ij
//   out[i,o] = (sum_j p_ij * hp[j,o]) / l_i + bias[o]
// LDS: P tile stored [j][i] so GEMM reads are float4-contiguous in i.
// ---------------------------------------------------------------------------
#define TJ 64
#define TI 64

__global__ __launch_bounds__(256, 2) void k_attn(
    const float* __restrict__ hp, const float* __restrict__ srcv,
    const float* __restrict__ dstv, const float* __restrict__ dmax,
    const float* __restrict__ bias, float* __restrict__ out)
{
  const int bh = blockIdx.y;
  const int i0 = blockIdx.x * TI;
  const int tid = threadIdx.x;

  __shared__ __align__(16) float Psh[TJ][TI];   // [j][i]
  __shared__ __align__(16) float Hsh[TJ][FOUT]; // [j][o]
  __shared__ float dsh[TJ];
  __shared__ float lsh[4][TI];

  const float* srcp = srcv + (size_t)bh*NSEQ + i0;
  const float* dstp = dstv + (size_t)bh*NSEQ;
  const float* hpp  = hp   + (size_t)bh*NSEQ*FOUT;

  // P-phase mapping: lane i, 4 j-groups of 16
  const int il   = tid & 63;
  const int jgrp = tid >> 6;
  const float s_i = srcp[il];
  const float dm  = dmax[bh];
  float m_i = s_i + dm;  m_i = (m_i >= 0.f) ? m_i : 0.2f*m_i;
  float lpart = 0.f;

  // GEMM mapping: 4x4 register tile per thread
  const int o_base = (tid & 15) * 4;
  const int i_base = (tid >> 4) * 4;
  float acc[4][4] = {{0.f}};

  for (int jt = 0; jt < NSEQ; jt += TJ){
    if (tid < TJ) dsh[tid] = dstp[jt + tid];
    // stage h_prime tile (float4 coalesced)
    const float4* hp4 = (const float4*)(hpp + (size_t)jt*FOUT);
    float4* H4 = (float4*)(&Hsh[0][0]);
    #pragma unroll
    for (int idx = tid; idx < TJ*FOUT/4; idx += 256) H4[idx] = hp4[idx];
    __syncthreads();

    // P tile: p = exp(lrelu(s_i + d_j) - m_i)  (arg <= 0 by construction)
    const int jb = jgrp * 16;
    #pragma unroll
    for (int jj = 0; jj < 16; ++jj){
      float x = s_i + dsh[jb + jj];
      x = (x >= 0.f) ? x : 0.2f*x;
      float p = __expf(x - m_i);
      Psh[jb + jj][il] = p;
      lpart += p;
    }
    __syncthreads();

    // GEMM: acc[ii][oo4] += P[j][i_base+ii] * H[j][o_base+oo4]
    #pragma unroll 4
    for (int j = 0; j < TJ; ++j){
      const float4 pv = *(const float4*)(&Psh[j][i_base]);
      const float4 hv = *(const float4*)(&Hsh[j][o_base]);
      acc[0][0] = fmaf(pv.x, hv.x, acc[0][0]);
      acc[0][1] = fmaf(pv.x, hv.y, acc[0][1]);
      acc[0][2] = fmaf(pv.x, hv.z, acc[0][2]);
      acc[0][3] = fmaf(pv.x, hv.w, acc[0][3]);
      acc[1][0] = fmaf(pv.y, hv.x, acc[1][0]);
      acc[1][1] = fmaf(pv.y, hv.y, acc[1][1]);
      acc[1][2] = fmaf(pv.y, hv.z, acc[1][2]);
      acc[1][3] = fmaf(pv.y, hv.w, acc[1][3]);
      acc[2][0] = fmaf(pv.z, hv.x, acc[2][0]);
      acc[2][1] = fmaf(pv.z, hv.y, acc[2][1]);
      acc[2][2] = fmaf(pv.z, hv.z, acc[2][2]);
      acc[2][3] = fmaf(pv.z, hv.w, acc[2][3]);
      acc[3][0] = fmaf(pv.w, hv.x, acc[3][0]);
      acc[3][1] = fmaf(pv.w, hv.y, acc[3][1]);
      acc[3][2] = fmaf(pv.w, hv.z, acc[3][2]);
      acc[3][3] = fmaf(pv.w, hv.w, acc[3][3]);
    }
    __syncthreads();
  }

  lsh[jgrp][il] = lpart;
  __syncthreads();

  float bo[4];
  #pragma unroll
  for (int k = 0; k < 4; ++k) bo[k] = bias[o_base + k];

  #pragma unroll
  for (int ii = 0; ii < 4; ++ii){
    const int i = i_base + ii;
    const float l = fmaxf(lsh[0][i] + lsh[1][i] + lsh[2][i] + lsh[3][i], 1e-30f);
    const float rinv = 1.f / l;
    float4 res;
    res.x = fmaf(acc[ii][0], rinv, bo[0]);
    res.y = fmaf(acc[ii][1], rinv, bo[1]);
    res.z = fmaf(acc[ii][2], rinv, bo[2]);
    res.w = fmaf(acc[ii][3], rinv, bo[3]);
    *(float4*)(out + ((size_t)bh*NSEQ + (i0 + i))*FOUT + o_base) = res;
  }
}

// ---------------------------------------------------------------------------
extern "C" void kernel_launch(void* const* d_in, const int* in_sizes, int n_in,
                              void* d_out, int out_size, void* d_ws, size_t ws_size,
                              hipStream_t stream)
{
  const float* h     = (const float*)d_in[0];
  const float* w     = (const float*)d_in[1];
  const float* a_src = (const float*)d_in[2];
  const float* a_dst = (const float*)d_in[3];
  const float* bias  = (const float*)d_in[4];
  float* out = (float*)d_out;

  float* hp   = (float*)d_ws;                                   // [16,2048,64] fp32
  float* srcv = hp + (size_t)BSZ*NHEAD*NSEQ*FOUT;               // [16,2048]
  float* dstv = srcv + (size_t)BSZ*NHEAD*NSEQ;                  // [16,2048]
  float* dmax = dstv + (size_t)BSZ*NHEAD*NSEQ;                  // [16]

  k_hprime<<<BSZ*NSEQ/4, 256, 0, stream>>>(h, w, a_src, a_dst, hp, srcv, dstv);
  k_dmax<<<BSZ*NHEAD, 256, 0, stream>>>(dstv, dmax);
  k_attn<<<dim3(NSEQ/TI, BSZ*NHEAD), 256, 0, stream>>>(hp, srcv, dstv, dmax, bias, out);
}

// Round 4
// 128.205 us; speedup vs baseline: 2.3840x; 2.3840x over previous
//
#include <hip/hip_runtime.h>
#include <hip/hip_bf16.h>

#define NHEAD 4
#define FIN   768
#define FOUT  64
#define BSZ   4
#define NSEQ  2048
#define BH    (BSZ*NHEAD)

typedef __attribute__((ext_vector_type(8))) short bf16x8;   // MFMA A/B frag (8 bf16)
typedef __attribute__((ext_vector_type(4))) float f32x4;    // MFMA C/D frag
typedef __attribute__((ext_vector_type(8))) unsigned short u16x8;
typedef __attribute__((ext_vector_type(4))) unsigned short u16x4;

// fp32 -> bf16 round-to-nearest-even (finite inputs only)
__device__ __forceinline__ unsigned short f2bf(float f){
  unsigned b = __float_as_uint(f);
  return (unsigned short)((b + 0x7fffu + ((b >> 16) & 1u)) >> 16);
}
// order-preserving float<->uint encoding for atomicMax (memset-0 == -inf)
__device__ __forceinline__ unsigned fenc(float f){
  unsigned b = __float_as_uint(f);
  return (b & 0x80000000u) ? ~b : (b | 0x80000000u);
}
__device__ __forceinline__ float fdec(unsigned u){
  unsigned b = (u & 0x80000000u) ? (u ^ 0x80000000u) : ~u;
  return __uint_as_float(b);
}

// ---------------------------------------------------------------------------
// Prep: w fp32 [4][768][64] -> bf16 frag-ready image
// layout: [head][kt(12)][o(64)][8 chunk-slots of 16B], slot = c ^ (o&7),
// chunk c holds k-local c*8..c*8+7 (k-local in [0,64) = f - kt*64).
// ---------------------------------------------------------------------------
__global__ __launch_bounds__(256) void k_prep_w(
    const float* __restrict__ w, unsigned short* __restrict__ wp)
{
  const int head = blockIdx.x, kt = blockIdx.y;
  #pragma unroll
  for (int p = 0; p < 2; ++p){
    int u = threadIdx.x + p*256;
    int o = u >> 3, c = u & 7;
    u16x8 pk;
    #pragma unroll
    for (int j = 0; j < 8; ++j){
      float v = w[((size_t)head*FIN + kt*64 + c*8 + j)*FOUT + o];
      pk[j] = f2bf(v);
    }
    int slot = c ^ (o & 7);
    *(u16x8*)((char*)wp + ((size_t)((head*12 + kt)*64 + o))*128 + slot*16) = pk;
  }
}

// ---------------------------------------------------------------------------
// Kernel A: h' = h @ w_head (MFMA bf16, fp32 acc), per-block 64 rows x 64 o.
// 512 thr = 8 waves: (wm,wn) 2x2 C-quadrants of 16x16x32 tiles, kw in {0,1}
// splits each K-step-64; partial accs merged through LDS.
// Epilogue: srcv/dstv tanh-reductions (fp32), dmax via encoded atomicMax,
// hp written bf16 TRANSPOSED+SWIZZLED [bh][o][j] (frag-ready for k_attn).
// ---------------------------------------------------------------------------
__global__ __launch_bounds__(512, 2) void k_hprime(
    const float* __restrict__ h, const unsigned short* __restrict__ wp,
    const float* __restrict__ a_src, const float* __restrict__ a_dst,
    unsigned short* __restrict__ hpz, float* __restrict__ srcv,
    float* __restrict__ dstv, unsigned* __restrict__ dmaxe)
{
  __shared__ __align__(16) char smem[16384];
  char* Ash = smem;            // 64 rows x 128B (swizzled chunks)
  char* Bsh = smem + 8192;     // 64 o-rows x 128B
  const int tid  = threadIdx.x;
  const int i0a  = blockIdx.x * 64;       // global flat row (b*2048+n)
  const int jbase = i0a & (NSEQ-1);       // within-sequence index  <-- R3 FIX
  const int head = blockIdx.y;
  const int wave = tid >> 6, lane = tid & 63;
  const int wm = (wave >> 1) & 1, wn = wave & 1, kw = wave >> 2;
  const int quad = lane >> 4, l16 = lane & 15;

  f32x4 acc[2][2] = {};

  const int sr = tid >> 3, sc = tid & 7;  // staging: row, chunk
  const float* hsrc = h + (size_t)(i0a + sr)*FIN + sc*8;
  const char* wblock = (const char*)wp + (size_t)head*12*8192;

  for (int kt = 0; kt < 12; ++kt){
    // stage A: fp32 -> bf16 convert into swizzled image
    float4 v0 = *(const float4*)(hsrc + kt*64);
    float4 v1 = *(const float4*)(hsrc + kt*64 + 4);
    u16x8 pk;
    pk[0]=f2bf(v0.x); pk[1]=f2bf(v0.y); pk[2]=f2bf(v0.z); pk[3]=f2bf(v0.w);
    pk[4]=f2bf(v1.x); pk[5]=f2bf(v1.y); pk[6]=f2bf(v1.z); pk[7]=f2bf(v1.w);
    *(u16x8*)(Ash + sr*128 + ((sc ^ (sr & 7)) << 4)) = pk;
    // stage B: linear copy of prepped image
    *(u16x8*)(Bsh + tid*16) = *(const u16x8*)(wblock + (size_t)kt*8192 + tid*16);
    __syncthreads();

    const int fslot = (((kw << 2) + quad) ^ (l16 & 7)) << 4;  // chunk c = kw*4+quad
    bf16x8 a0 = *(const bf16x8*)(Ash + (wm*32      + l16)*128 + fslot);
    bf16x8 a1 = *(const bf16x8*)(Ash + (wm*32 + 16 + l16)*128 + fslot);
    bf16x8 b0 = *(const bf16x8*)(Bsh + (wn*32      + l16)*128 + fslot);
    bf16x8 b1 = *(const bf16x8*)(Bsh + (wn*32 + 16 + l16)*128 + fslot);
    acc[0][0] = __builtin_amdgcn_mfma_f32_16x16x32_bf16(a0, b0, acc[0][0], 0,0,0);
    acc[0][1] = __builtin_amdgcn_mfma_f32_16x16x32_bf16(a0, b1, acc[0][1], 0,0,0);
    acc[1][0] = __builtin_amdgcn_mfma_f32_16x16x32_bf16(a1, b0, acc[1][0], 0,0,0);
    acc[1][1] = __builtin_amdgcn_mfma_f32_16x16x32_bf16(a1, b1, acc[1][1], 0,0,0);
    __syncthreads();
  }

  // merge kw=1 partials into kw=0 waves (scratch aliases Ash/Bsh, 16KB)
  if (kw == 1){
    char* scr = smem + ((size_t)(wave & 3)*64 + lane)*64;
    *(f32x4*)(scr     ) = acc[0][0]; *(f32x4*)(scr + 16) = acc[0][1];
    *(f32x4*)(scr + 32) = acc[1][0]; *(f32x4*)(scr + 48) = acc[1][1];
  }
  __syncthreads();
  if (kw == 0){
    char* scr = smem + ((size_t)wave*64 + lane)*64;
    acc[0][0] += *(const f32x4*)(scr     ); acc[0][1] += *(const f32x4*)(scr + 16);
    acc[1][0] += *(const f32x4*)(scr + 32); acc[1][1] += *(const f32x4*)(scr + 48);
  }
  __syncthreads();   // scratch reads done; smem reusable

  float* psumS = (float*)(smem + 8192);   // [64][2]
  float* psumD = psumS + 128;             // [64][2]

  if (kw == 0){
    const float as0 = a_src[head*64 + wn*32 + l16];
    const float as1 = a_src[head*64 + wn*32 + 16 + l16];
    const float ad0 = a_dst[head*64 + wn*32 + l16];
    const float ad1 = a_dst[head*64 + wn*32 + 16 + l16];
    #pragma unroll
    for (int mi = 0; mi < 2; ++mi){
      const int rbase = wm*32 + mi*16 + quad*4;   // C row = sequence row
      #pragma unroll
      for (int reg = 0; reg < 4; ++reg){
        float vA = acc[mi][0][reg], vB = acc[mi][1][reg];
        float t0 = tanhf(vA), t1 = tanhf(vB);
        float ps = t0*as0 + t1*as1;
        float pd = t0*ad0 + t1*ad1;
        ps += __shfl_xor(ps, 1); ps += __shfl_xor(ps, 2);
        ps += __shfl_xor(ps, 4); ps += __shfl_xor(ps, 8);
        pd += __shfl_xor(pd, 1); pd += __shfl_xor(pd, 2);
        pd += __shfl_xor(pd, 4); pd += __shfl_xor(pd, 8);
        if (l16 == 0){
          psumS[(rbase + reg)*2 + wn] = ps;
          psumD[(rbase + reg)*2 + wn] = pd;
        }
      }
      // transpose C into smem[0..8192): rows = o, swizzled j-chunks
      #pragma unroll
      for (int ni = 0; ni < 2; ++ni){
        const int orow = wn*32 + ni*16 + l16;
        u16x4 c4;
        c4[0] = f2bf(acc[mi][ni][0]); c4[1] = f2bf(acc[mi][ni][1]);
        c4[2] = f2bf(acc[mi][ni][2]); c4[3] = f2bf(acc[mi][ni][3]);
        const int slot = ((rbase >> 3) & 7) ^ (orow & 7);
        *(u16x4*)(smem + orow*128 + slot*16 + (rbase & 7)*2) = c4;
      }
    }
  }
  __syncthreads();

  // cooperative store of the 8KB transposed tile into hp_swz[bh][o][jbase..+64]
  const int bh = (i0a >> 11)*NHEAD + head;
  {
    const int o = tid >> 3, part = tid & 7;
    u16x8 val = *(const u16x8*)(smem + o*128 + part*16);
    *(u16x8*)((char*)hpz + ((size_t)(bh*64 + o)*NSEQ + jbase)*2 + part*16) = val;
  }
  if (tid < 64){
    float sv = psumS[tid*2] + psumS[tid*2 + 1];
    float dv = psumD[tid*2] + psumD[tid*2 + 1];
    srcv[(size_t)bh*NSEQ + jbase + tid] = sv;
    dstv[(size_t)bh*NSEQ + jbase + tid] = dv;
    float dmx = dv;
    dmx = fmaxf(dmx, __shfl_xor(dmx, 1));  dmx = fmaxf(dmx, __shfl_xor(dmx, 2));
    dmx = fmaxf(dmx, __shfl_xor(dmx, 4));  dmx = fmaxf(dmx, __shfl_xor(dmx, 8));
    dmx = fmaxf(dmx, __shfl_xor(dmx, 16)); dmx = fmaxf(dmx, __shfl_xor(dmx, 32));
    if (tid == 0) atomicMax(&dmaxe[bh], fenc(dmx));
  }
}

// ---------------------------------------------------------------------------
// Kernel B: flash-style softmax(leakyrelu(src_i+dst_j)) @ h'  via MFMA.
// Exact row max m_i = lrelu(s_i + dmax) (lrelu monotone). Per block:
// 64 i-rows x 64 o, j-loop step 64. P computed fp32->bf16 into LDS.
// ---------------------------------------------------------------------------
__global__ __launch_bounds__(512, 2) void k_attn(
    const unsigned short* __restrict__ hpz, const float* __restrict__ srcv,
    const float* __restrict__ dstv, const unsigned* __restrict__ dmaxe,
    const float* __restrict__ bias, float* __restrict__ out)
{
  __shared__ __align__(16) char smem[26880];
  float* dsh  = (float*)smem;              // 2048 fp32 (8KB)
  char*  Psh  = smem + 8192;               // 64 i x 128B
  char*  Hsh  = smem + 16384;              // 64 o x 128B
  float* lsum = (float*)(smem + 24576);    // [512]
  float* linv = (float*)(smem + 26624);    // [64]

  const int tid = threadIdx.x;
  const int i0  = blockIdx.x * 64;
  const int bh  = blockIdx.y;
  const int wave = tid >> 6, lane = tid & 63;
  const int wm = (wave >> 1) & 1, wn = wave & 1, kw = wave >> 2;
  const int quad = lane >> 4, l16 = lane & 15;

  // preload all d_j for this bh
  *(float4*)(dsh + tid*4) = *(const float4*)(dstv + (size_t)bh*NSEQ + tid*4);

  const int ip = tid >> 3, cch = tid & 7;   // P row / j-chunk for this thread
  const float s  = srcv[(size_t)bh*NSEQ + i0 + ip];
  const float dm = fdec(dmaxe[bh]);
  float mrow = s + dm; mrow = fmaxf(mrow, 0.2f*mrow);   // exact row max (lrelu)
  float lpart = 0.f;
  f32x4 acc[2][2] = {};
  const int pslot = (cch ^ (ip & 7)) << 4;
  const char* hsrc = (const char*)hpz + (size_t)(bh*64 + ip)*NSEQ*2 + cch*16;
  __syncthreads();   // dsh ready

  for (int jt = 0; jt < NSEQ; jt += 64){
    // stage H (linear copy, already frag-ready) + compute P chunk
    *(u16x8*)(Hsh + tid*16) = *(const u16x8*)(hsrc + jt*2);
    u16x8 pk;
    #pragma unroll
    for (int j = 0; j < 8; ++j){
      float x = s + dsh[jt + cch*8 + j];
      x = fmaxf(x, 0.2f*x);                 // leaky_relu
      float ev = __expf(x - mrow);          // arg <= 0 by construction
      lpart += ev;
      pk[j] = f2bf(ev);
    }
    *(u16x8*)(Psh + ip*128 + pslot) = pk;
    __syncthreads();

    const int fslot = (((kw << 2) + quad) ^ (l16 & 7)) << 4;
    bf16x8 a0 = *(const bf16x8*)(Psh + (wm*32      + l16)*128 + fslot);
    bf16x8 a1 = *(const bf16x8*)(Psh + (wm*32 + 16 + l16)*128 + fslot);
    bf16x8 b0 = *(const bf16x8*)(Hsh + (wn*32      + l16)*128 + fslot);
    bf16x8 b1 = *(const bf16x8*)(Hsh + (wn*32 + 16 + l16)*128 + fslot);
    acc[0][0] = __builtin_amdgcn_mfma_f32_16x16x32_bf16(a0, b0, acc[0][0], 0,0,0);
    acc[0][1] = __builtin_amdgcn_mfma_f32_16x16x32_bf16(a0, b1, acc[0][1], 0,0,0);
    acc[1][0] = __builtin_amdgcn_mfma_f32_16x16x32_bf16(a1, b0, acc[1][0], 0,0,0);
    acc[1][1] = __builtin_amdgcn_mfma_f32_16x16x32_bf16(a1, b1, acc[1][1], 0,0,0);
    __syncthreads();
  }

  lsum[tid] = lpart;
  if (kw == 1){
    char* scr = smem + 8192 + ((size_t)(wave & 3)*64 + lane)*64;
    *(f32x4*)(scr     ) = acc[0][0]; *(f32x4*)(scr + 16) = acc[0][1];
    *(f32x4*)(scr + 32) = acc[1][0]; *(f32x4*)(scr + 48) = acc[1][1];
  }
  __syncthreads();
  if (kw == 0){
    char* scr = smem + 8192 + ((size_t)wave*64 + lane)*64;
    acc[0][0] += *(const f32x4*)(scr     ); acc[0][1] += *(const f32x4*)(scr + 16);
    acc[1][0] += *(const f32x4*)(scr + 32); acc[1][1] += *(const f32x4*)(scr + 48);
  }
  if (tid < 64){
    float l = 0.f;
    #pragma unroll
    for (int c = 0; c < 8; ++c) l += lsum[tid*8 + c];
    linv[tid] = 1.f / l;     // l >= 1 always (exp(0) term present)
  }
  __syncthreads();

  if (kw == 0){
    const float bv0 = bias[wn*32 + l16];
    const float bv1 = bias[wn*32 + 16 + l16];
    #pragma unroll
    for (int mi = 0; mi < 2; ++mi){
      const int ibase = wm*32 + mi*16 + quad*4;
      #pragma unroll
      for (int reg = 0; reg < 4; ++reg){
        const float ri = linv[ibase + reg];
        float* op = out + ((size_t)bh*NSEQ + i0 + ibase + reg)*64;
        op[wn*32      + l16] = acc[mi][0][reg]*ri + bv0;
        op[wn*32 + 16 + l16] = acc[mi][1][reg]*ri + bv1;
      }
    }
  }
}

// ---------------------------------------------------------------------------
extern "C" void kernel_launch(void* const* d_in, const int* in_sizes, int n_in,
                              void* d_out, int out_size, void* d_ws, size_t ws_size,
                              hipStream_t stream)
{
  const float* h     = (const float*)d_in[0];
  const float* w     = (const float*)d_in[1];
  const float* a_src = (const float*)d_in[2];
  const float* a_dst = (const float*)d_in[3];
  const float* bias  = (const float*)d_in[4];
  float* out = (float*)d_out;

  char* ws = (char*)d_ws;
  unsigned short* hpz = (unsigned short*)ws;                            // 4 MB  bf16 [16][64][2048] swizzled
  float* srcv = (float*)(ws + (4u<<20));                                // 128KB
  float* dstv = (float*)(ws + (4u<<20) + (128u<<10));                   // 128KB
  unsigned short* wp = (unsigned short*)(ws + (4u<<20) + (256u<<10));   // 384KB
  unsigned* dmaxe = (unsigned*)(ws + (4u<<20) + (640u<<10));            // 64B

  hipMemsetAsync(dmaxe, 0, BH*sizeof(unsigned), stream);
  k_prep_w<<<dim3(NHEAD, 12), 256, 0, stream>>>(w, wp);
  k_hprime<<<dim3(NSEQ*BSZ/64, NHEAD), 512, 0, stream>>>(h, wp, a_src, a_dst,
                                                         hpz, srcv, dstv, dmaxe);
  k_attn<<<dim3(NSEQ/64, BH), 512, 0, stream>>>(hpz, srcv, dstv, dmaxe, bias, out);
}

// Round 5
// 125.558 us; speedup vs baseline: 2.4342x; 1.0211x over previous
//
#include <hip/hip_runtime.h>
#include <hip/hip_bf16.h>

#define NHEAD 4
#define FIN   768
#define FOUT  64
#define BSZ   4
#define NSEQ  2048
#define BH    (BSZ*NHEAD)

typedef __attribute__((ext_vector_type(8)))  short bf16x8;   // MFMA A/B frag
typedef __attribute__((ext_vector_type(16))) float f32x16;   // MFMA 32x32 C/D
typedef __attribute__((ext_vector_type(8)))  unsigned short u16x8;
typedef __attribute__((ext_vector_type(4)))  unsigned short u16x4;

__device__ __forceinline__ unsigned short f2bf(float f){
  unsigned b = __float_as_uint(f);
  return (unsigned short)((b + 0x7fffu + ((b >> 16) & 1u)) >> 16);
}
__device__ __forceinline__ unsigned fenc(float f){
  unsigned b = __float_as_uint(f);
  return (b & 0x80000000u) ? ~b : (b | 0x80000000u);
}
__device__ __forceinline__ float fdec(unsigned u){
  unsigned b = (u & 0x80000000u) ? (u ^ 0x80000000u) : ~u;
  return __uint_as_float(b);
}
__device__ __forceinline__ float pexp(float s, float d, float m){
  float x = s + d;
  x = fmaxf(x, 0.2f*x);          // leaky_relu
  return __expf(x - m);          // arg <= 0 by construction
}

// ---------------------------------------------------------------------------
// Prep: w fp32 [4][768][64] -> bf16 frag image [head][12 panels of 64k][o][slot]
// slot = c ^ (o&7), chunk c = 8 k-elems. Also zeroes dmaxe (drops a memset).
// ---------------------------------------------------------------------------
__global__ __launch_bounds__(256) void k_prep_w(
    const float* __restrict__ w, unsigned short* __restrict__ wp,
    unsigned* __restrict__ dmaxe)
{
  if (blockIdx.x == 0 && blockIdx.y == 0 && threadIdx.x < BH)
    dmaxe[threadIdx.x] = 0;                  // fenc(-inf) order: 0 = minimum
  const int head = blockIdx.x, kt = blockIdx.y;
  #pragma unroll
  for (int p = 0; p < 2; ++p){
    int u = threadIdx.x + p*256;
    int o = u >> 3, c = u & 7;
    u16x8 pk;
    #pragma unroll
    for (int j = 0; j < 8; ++j)
      pk[j] = f2bf(w[((size_t)head*FIN + kt*64 + c*8 + j)*FOUT + o]);
    *(u16x8*)((char*)wp + ((size_t)((head*12 + kt)*64 + o))*128 + (c ^ (o & 7))*16) = pk;
  }
}

// ---------------------------------------------------------------------------
// Kernel A: h' = h @ w_head via 32x32x16 MFMA. 64 rows x 64 o per block.
// 512 thr = 8 waves (wm,wn,kw) = 2x2x2; K-tile 128, 6 iters, double-buffered
// LDS, 1 barrier/iter, register prefetch of next A/B tiles.
// Epilogue: kw-merge, tanh/src/dst reductions, dmax atomic, hpz bf16
// transposed+swizzled [bh][o][j].
// ---------------------------------------------------------------------------
__global__ __launch_bounds__(512, 4) void k_hprime(
    const float* __restrict__ h, const unsigned short* __restrict__ wp,
    const float* __restrict__ a_src, const float* __restrict__ a_dst,
    unsigned short* __restrict__ hpz, float* __restrict__ srcv,
    float* __restrict__ dstv, unsigned* __restrict__ dmaxe)
{
  __shared__ __align__(16) char smem[65536];
  // Ash0 @0, Ash1 @16384, Bsh0 @32768, Bsh1 @49152
  // overlays (epilogue only): scratch @0 (16K), psumS @16384, psumD @16896, T @32768 (8K)
  float* psumS = (float*)(smem + 16384);
  float* psumD = (float*)(smem + 16896);
  char*  Tt    = smem + 32768;

  const int tid  = threadIdx.x;
  const int i0a  = blockIdx.x * 64;
  const int jbase = i0a & (NSEQ-1);
  const int head = blockIdx.y;
  const int wave = tid >> 6, lane = tid & 63;
  const int wm = wave & 1, wn = (wave >> 1) & 1, kw = wave >> 2;
  const int l32 = lane & 31, h32 = lane >> 5;

  f32x16 acc = {0,0,0,0,0,0,0,0,0,0,0,0,0,0,0,0};

  const int sr = tid >> 3, sc = tid & 7;
  const float* hA = h + (size_t)(i0a + sr)*FIN + sc*8;
  const char*  wB = (const char*)wp + ((size_t)(head*12*64 + sr))*128 + sc*16;
  const int aslot = (sc ^ (sr & 7)) << 4;

  // prologue: prefetch iter 0
  float4 ra0 = *(const float4*)(hA);
  float4 ra1 = *(const float4*)(hA + 4);
  float4 ra2 = *(const float4*)(hA + 64);
  float4 ra3 = *(const float4*)(hA + 68);
  u16x8  rb0 = *(const u16x8*)(wB);
  u16x8  rb1 = *(const u16x8*)(wB + 8192);

  for (int it = 0; it < 6; ++it){
    char* Ab = smem + (it & 1)*16384;
    char* Bb = smem + 32768 + (it & 1)*16384;
    u16x8 pk0, pk1;
    pk0[0]=f2bf(ra0.x); pk0[1]=f2bf(ra0.y); pk0[2]=f2bf(ra0.z); pk0[3]=f2bf(ra0.w);
    pk0[4]=f2bf(ra1.x); pk0[5]=f2bf(ra1.y); pk0[6]=f2bf(ra1.z); pk0[7]=f2bf(ra1.w);
    pk1[0]=f2bf(ra2.x); pk1[1]=f2bf(ra2.y); pk1[2]=f2bf(ra2.z); pk1[3]=f2bf(ra2.w);
    pk1[4]=f2bf(ra3.x); pk1[5]=f2bf(ra3.y); pk1[6]=f2bf(ra3.z); pk1[7]=f2bf(ra3.w);
    *(u16x8*)(Ab + sr*256 + aslot)        = pk0;
    *(u16x8*)(Ab + sr*256 + 128 + aslot)  = pk1;
    *(u16x8*)(Bb + sr*256 + sc*16)        = rb0;
    *(u16x8*)(Bb + sr*256 + 128 + sc*16)  = rb1;
    __syncthreads();
    if (it < 5){
      const float* an = hA + (it+1)*128;
      ra0 = *(const float4*)(an);      ra1 = *(const float4*)(an + 4);
      ra2 = *(const float4*)(an + 64); ra3 = *(const float4*)(an + 68);
      const char* bn = wB + (size_t)(2*(it+1))*8192;
      rb0 = *(const u16x8*)(bn);       rb1 = *(const u16x8*)(bn + 8192);
    }
    #pragma unroll
    for (int s = 0; s < 4; ++s){
      const int slot = (((s*2 + h32) ^ (l32 & 7)) << 4);
      bf16x8 av = *(const bf16x8*)(Ab + (wm*32 + l32)*256 + kw*128 + slot);
      bf16x8 bv = *(const bf16x8*)(Bb + (wn*32 + l32)*256 + kw*128 + slot);
      acc = __builtin_amdgcn_mfma_f32_32x32x16_bf16(av, bv, acc, 0, 0, 0);
    }
  }

  // kw-merge through scratch (Ash0 region; its last readers finished pre-barrier(5))
  if (kw == 1) *(f32x16*)(smem + (size_t)((wave & 3)*64 + lane)*64) = acc;
  __syncthreads();
  if (kw == 0){
    acc += *(const f32x16*)(smem + (size_t)((wave & 3)*64 + lane)*64);
    const float as = a_src[head*64 + wn*32 + l32];
    const float ad = a_dst[head*64 + wn*32 + l32];
    #pragma unroll
    for (int rb = 0; rb < 4; ++rb){
      const int jb = wm*32 + rb*8 + h32*4;       // 4 consecutive seq-rows
      u16x4 c4;
      #pragma unroll
      for (int q = 0; q < 4; ++q){
        const float v = acc[rb*4 + q];
        c4[q] = f2bf(v);
        const float t = tanhf(v);
        float ps = t*as, pd = t*ad;
        ps += __shfl_xor(ps, 1);  ps += __shfl_xor(ps, 2);  ps += __shfl_xor(ps, 4);
        ps += __shfl_xor(ps, 8);  ps += __shfl_xor(ps, 16);
        pd += __shfl_xor(pd, 1);  pd += __shfl_xor(pd, 2);  pd += __shfl_xor(pd, 4);
        pd += __shfl_xor(pd, 8);  pd += __shfl_xor(pd, 16);
        if (l32 == 0){
          psumS[(jb + q)*2 + wn] = ps;
          psumD[(jb + q)*2 + wn] = pd;
        }
      }
      const int orow = wn*32 + l32;
      const int slot = ((jb >> 3) & 7) ^ (orow & 7);
      *(u16x4*)(Tt + orow*128 + slot*16 + (jb & 7)*2) = c4;
    }
  }
  __syncthreads();

  const int bh = (i0a >> 11)*NHEAD + head;
  *(u16x8*)((char*)hpz + ((size_t)(bh*64 + sr)*NSEQ + jbase)*2 + sc*16)
      = *(const u16x8*)(Tt + sr*128 + sc*16);
  if (tid < 64){
    float sv = psumS[tid*2] + psumS[tid*2 + 1];
    float dv = psumD[tid*2] + psumD[tid*2 + 1];
    srcv[(size_t)bh*NSEQ + jbase + tid] = sv;
    dstv[(size_t)bh*NSEQ + jbase + tid] = dv;
    float dmx = dv;
    dmx = fmaxf(dmx, __shfl_xor(dmx, 1));  dmx = fmaxf(dmx, __shfl_xor(dmx, 2));
    dmx = fmaxf(dmx, __shfl_xor(dmx, 4));  dmx = fmaxf(dmx, __shfl_xor(dmx, 8));
    dmx = fmaxf(dmx, __shfl_xor(dmx, 16)); dmx = fmaxf(dmx, __shfl_xor(dmx, 32));
    if (tid == 0) atomicMax(&dmaxe[bh], fenc(dmx));
  }
}

// ---------------------------------------------------------------------------
// Kernel B: softmax(lrelu(s_i+d_j)) @ h' via 32x32x16 MFMA, exact one-pass max.
// 64 i x 64 o per block; j-step 128, 16 iters, double-buffered, 1 barrier/iter.
// d_j from global (L1), P fp32->bf16 into LDS, H staged linearly (pre-swizzled).
// ---------------------------------------------------------------------------
__global__ __launch_bounds__(512, 4) void k_attn(
    const unsigned short* __restrict__ hpz, const float* __restrict__ srcv,
    const float* __restrict__ dstv, const unsigned* __restrict__ dmaxe,
    const float* __restrict__ bias, float* __restrict__ out)
{
  __shared__ __align__(16) char smem[65536];
  // Psh0 @0, Psh1 @16384, Hsh0 @32768, Hsh1 @49152
  // overlays (epilogue): scratch @0 (16K), lrow @32768, linv @33024
  float* lrow = (float*)(smem + 32768);
  float* linv = (float*)(smem + 33024);

  const int tid = threadIdx.x;
  const int i0  = blockIdx.x * 64;
  const int bh  = blockIdx.y;
  const int wave = tid >> 6, lane = tid & 63;
  const int wm = wave & 1, wn = (wave >> 1) & 1, kw = wave >> 2;
  const int l32 = lane & 31, h32 = lane >> 5;
  const int ip = tid >> 3, cch = tid & 7;

  const float s  = srcv[(size_t)bh*NSEQ + i0 + ip];
  const float dm = fdec(dmaxe[bh]);
  float mrow = s + dm; mrow = fmaxf(mrow, 0.2f*mrow);   // exact row max (lrelu monotone)
  float lpart = 0.f;

  const float* dsrc = dstv + (size_t)bh*NSEQ + cch*8;
  const char*  hsrc = (const char*)hpz + ((size_t)(bh*64 + ip)*NSEQ)*2 + cch*16;
  const int pslot = (cch ^ (ip & 7)) << 4;

  f32x16 acc = {0,0,0,0,0,0,0,0,0,0,0,0,0,0,0,0};

  // prologue: prefetch iter 0
  u16x8 hA = *(const u16x8*)(hsrc);
  u16x8 hB = *(const u16x8*)(hsrc + 128);
  u16x8 pA, pB;
  {
    float4 d0 = *(const float4*)(dsrc);
    float4 d1 = *(const float4*)(dsrc + 4);
    float4 d2 = *(const float4*)(dsrc + 64);
    float4 d3 = *(const float4*)(dsrc + 68);
    float e;
    e=pexp(s,d0.x,mrow); lpart+=e; pA[0]=f2bf(e);  e=pexp(s,d0.y,mrow); lpart+=e; pA[1]=f2bf(e);
    e=pexp(s,d0.z,mrow); lpart+=e; pA[2]=f2bf(e);  e=pexp(s,d0.w,mrow); lpart+=e; pA[3]=f2bf(e);
    e=pexp(s,d1.x,mrow); lpart+=e; pA[4]=f2bf(e);  e=pexp(s,d1.y,mrow); lpart+=e; pA[5]=f2bf(e);
    e=pexp(s,d1.z,mrow); lpart+=e; pA[6]=f2bf(e);  e=pexp(s,d1.w,mrow); lpart+=e; pA[7]=f2bf(e);
    e=pexp(s,d2.x,mrow); lpart+=e; pB[0]=f2bf(e);  e=pexp(s,d2.y,mrow); lpart+=e; pB[1]=f2bf(e);
    e=pexp(s,d2.z,mrow); lpart+=e; pB[2]=f2bf(e);  e=pexp(s,d2.w,mrow); lpart+=e; pB[3]=f2bf(e);
    e=pexp(s,d3.x,mrow); lpart+=e; pB[4]=f2bf(e);  e=pexp(s,d3.y,mrow); lpart+=e; pB[5]=f2bf(e);
    e=pexp(s,d3.z,mrow); lpart+=e; pB[6]=f2bf(e);  e=pexp(s,d3.w,mrow); lpart+=e; pB[7]=f2bf(e);
  }

  for (int it = 0; it < 16; ++it){
    char* Pb = smem + (it & 1)*16384;
    char* Hb = smem + 32768 + (it & 1)*16384;
    *(u16x8*)(Pb + ip*256 + pslot)       = pA;
    *(u16x8*)(Pb + ip*256 + 128 + pslot) = pB;
    *(u16x8*)(Hb + ip*256 + cch*16)       = hA;
    *(u16x8*)(Hb + ip*256 + 128 + cch*16) = hB;
    __syncthreads();
    if (it < 15){
      const int jn = (it + 1)*128;
      hA = *(const u16x8*)(hsrc + jn*2);
      hB = *(const u16x8*)(hsrc + jn*2 + 128);
      const float* dn = dsrc + jn;
      float4 d0 = *(const float4*)(dn);
      float4 d1 = *(const float4*)(dn + 4);
      float4 d2 = *(const float4*)(dn + 64);
      float4 d3 = *(const float4*)(dn + 68);
      float e;
      e=pexp(s,d0.x,mrow); lpart+=e; pA[0]=f2bf(e);  e=pexp(s,d0.y,mrow); lpart+=e; pA[1]=f2bf(e);
      e=pexp(s,d0.z,mrow); lpart+=e; pA[2]=f2bf(e);  e=pexp(s,d0.w,mrow); lpart+=e; pA[3]=f2bf(e);
      e=pexp(s,d1.x,mrow); lpart+=e; pA[4]=f2bf(e);  e=pexp(s,d1.y,mrow); lpart+=e; pA[5]=f2bf(e);
      e=pexp(s,d1.z,mrow); lpart+=e; pA[6]=f2bf(e);  e=pexp(s,d1.w,mrow); lpart+=e; pA[7]=f2bf(e);
      e=pexp(s,d2.x,mrow); lpart+=e; pB[0]=f2bf(e);  e=pexp(s,d2.y,mrow); lpart+=e; pB[1]=f2bf(e);
      e=pexp(s,d2.z,mrow); lpart+=e; pB[2]=f2bf(e);  e=pexp(s,d2.w,mrow); lpart+=e; pB[3]=f2bf(e);
      e=pexp(s,d3.x,mrow); lpart+=e; pB[4]=f2bf(e);  e=pexp(s,d3.y,mrow); lpart+=e; pB[5]=f2bf(e);
      e=pexp(s,d3.z,mrow); lpart+=e; pB[6]=f2bf(e);  e=pexp(s,d3.w,mrow); lpart+=e; pB[7]=f2bf(e);
    }
    #pragma unroll
    for (int st = 0; st < 4; ++st){
      const int slot = (((st*2 + h32) ^ (l32 & 7)) << 4);
      bf16x8 av = *(const bf16x8*)(Pb + (wm*32 + l32)*256 + kw*128 + slot);
      bf16x8 bv = *(const bf16x8*)(Hb + (wn*32 + l32)*256 + kw*128 + slot);
      acc = __builtin_amdgcn_mfma_f32_32x32x16_bf16(av, bv, acc, 0, 0, 0);
    }
  }

  // row-sum merge (8 consecutive lanes per row), lrow overlays Hsh0 (dead)
  lpart += __shfl_xor(lpart, 1);
  lpart += __shfl_xor(lpart, 2);
  lpart += __shfl_xor(lpart, 4);
  if (cch == 0) lrow[ip] = lpart;
  if (kw == 1) *(f32x16*)(smem + (size_t)((wave & 3)*64 + lane)*64) = acc;
  __syncthreads();
  if (tid < 64) linv[tid] = 1.f / lrow[tid];     // l >= 1 (exp(0) term present)
  if (kw == 0)
    acc += *(const f32x16*)(smem + (size_t)((wave & 3)*64 + lane)*64);
  __syncthreads();

  if (kw == 0){
    const float bv = bias[wn*32 + l32];
    float* obase = out + ((size_t)bh*NSEQ + i0)*64 + wn*32 + l32;
    #pragma unroll
    for (int rb = 0; rb < 4; ++rb){
      #pragma unroll
      for (int q = 0; q < 4; ++q){
        const int irow = wm*32 + rb*8 + h32*4 + q;
        obase[(size_t)irow*64] = acc[rb*4 + q]*linv[irow] + bv;
      }
    }
  }
}

// ---------------------------------------------------------------------------
extern "C" void kernel_launch(void* const* d_in, const int* in_sizes, int n_in,
                              void* d_out, int out_size, void* d_ws, size_t ws_size,
                              hipStream_t stream)
{
  const float* h     = (const float*)d_in[0];
  const float* w     = (const float*)d_in[1];
  const float* a_src = (const float*)d_in[2];
  const float* a_dst = (const float*)d_in[3];
  const float* bias  = (const float*)d_in[4];
  float* out = (float*)d_out;

  char* ws = (char*)d_ws;
  unsigned short* hpz = (unsigned short*)ws;                            // 4 MB bf16 [16][64][2048] swizzled
  float* srcv = (float*)(ws + (4u<<20));                                // 128 KB
  float* dstv = (float*)(ws + (4u<<20) + (128u<<10));                   // 128 KB
  unsigned short* wp = (unsigned short*)(ws + (4u<<20) + (256u<<10));   // 384 KB
  unsigned* dmaxe = (unsigned*)(ws + (4u<<20) + (640u<<10));            // 64 B

  k_prep_w<<<dim3(NHEAD, 12), 256, 0, stream>>>(w, wp, dmaxe);
  k_hprime<<<dim3(NSEQ*BSZ/64, NHEAD), 512, 0, stream>>>(h, wp, a_src, a_dst,
                                                         hpz, srcv, dstv, dmaxe);
  k_attn<<<dim3(NSEQ/64, BH), 512, 0, stream>>>(hpz, srcv, dstv, dmaxe, bias, out);
}

// Round 6
// 122.993 us; speedup vs baseline: 2.4850x; 1.0209x over previous
//
#include <hip/hip_runtime.h>
#include <hip/hip_bf16.h>

#define NHEAD 4
#define FIN   768
#define FOUT  64
#define BSZ   4
#define NSEQ  2048
#define BH    (BSZ*NHEAD)
#define LOG2E 1.44269504088896f

typedef __attribute__((ext_vector_type(8)))  short bf16x8;   // MFMA A/B frag
typedef __attribute__((ext_vector_type(16))) float f32x16;   // MFMA 32x32 C/D
typedef __attribute__((ext_vector_type(8)))  unsigned short u16x8;
typedef __attribute__((ext_vector_type(4)))  unsigned short u16x4;
typedef __attribute__((ext_vector_type(4)))  unsigned u32x4;

__device__ __forceinline__ unsigned short f2bf(float f){
  unsigned b = __float_as_uint(f);
  return (unsigned short)((b + 0x7fffu + ((b >> 16) & 1u)) >> 16);
}
__device__ __forceinline__ unsigned fenc(float f){
  unsigned b = __float_as_uint(f);
  return (b & 0x80000000u) ? ~b : (b | 0x80000000u);
}
__device__ __forceinline__ float fdec(unsigned u){
  unsigned b = (u & 0x80000000u) ? (u ^ 0x80000000u) : ~u;
  return __uint_as_float(b);
}
__device__ __forceinline__ float fexp2(float x){
#if __has_builtin(__builtin_amdgcn_exp2f)
  return __builtin_amdgcn_exp2f(x);
#else
  return exp2f(x);
#endif
}
// pack two fp32 -> one dword of 2 bf16 (RNE)
__device__ __forceinline__ unsigned pkbf(float lo, float hi){
#if __has_builtin(__builtin_amdgcn_cvt_pk_bf16_f32)
  typedef __attribute__((ext_vector_type(2))) __bf16 bf2;
  union { bf2 v; unsigned u; } cv;
  cv.v = __builtin_amdgcn_cvt_pk_bf16_f32(lo, hi);
  return cv.u;
#else
  return (unsigned)f2bf(lo) | ((unsigned)f2bf(hi) << 16);
#endif
}

// ---------------------------------------------------------------------------
// Prep: w fp32 [4][768][64] -> bf16 frag image [head][12 panels][o][slot16B],
// slot = c ^ (o&7). Also zeroes dmaxe.
// ---------------------------------------------------------------------------
__global__ __launch_bounds__(256) void k_prep_w(
    const float* __restrict__ w, unsigned short* __restrict__ wp,
    unsigned* __restrict__ dmaxe)
{
  if (blockIdx.x == 0 && blockIdx.y == 0 && threadIdx.x < BH)
    dmaxe[threadIdx.x] = 0;
  const int head = blockIdx.x, kt = blockIdx.y;
  #pragma unroll
  for (int p = 0; p < 2; ++p){
    int u = threadIdx.x + p*256;
    int o = u >> 3, c = u & 7;
    u16x8 pk;
    #pragma unroll
    for (int j = 0; j < 8; ++j)
      pk[j] = f2bf(w[((size_t)head*FIN + kt*64 + c*8 + j)*FOUT + o]);
    *(u16x8*)((char*)wp + ((size_t)((head*12 + kt)*64 + o))*128 + (c ^ (o & 7))*16) = pk;
  }
}

// ---------------------------------------------------------------------------
// Kernel A: h' = h @ w_head via 32x32x16 MFMA (r5 core, PASSED).
// Epilogue changes vs r5: srcv/dstv pre-scaled by log2(e); hpz2 written
// CHUNK-LINEAR: chunk (J = j>>3, o) 16B at ((bh*256 + J)*64 + o)*16.
// ---------------------------------------------------------------------------
__global__ __launch_bounds__(512, 2) void k_hprime(
    const float* __restrict__ h, const unsigned short* __restrict__ wp,
    const float* __restrict__ a_src, const float* __restrict__ a_dst,
    unsigned short* __restrict__ hpz2, float* __restrict__ srcv,
    float* __restrict__ dstv, unsigned* __restrict__ dmaxe)
{
  __shared__ __align__(16) char smem[65536];
  float* psumS = (float*)(smem + 16384);
  float* psumD = (float*)(smem + 16896);
  char*  Tt    = smem + 32768;

  const int tid  = threadIdx.x;
  const int i0a  = blockIdx.x * 64;
  const int jbase = i0a & (NSEQ-1);
  const int head = blockIdx.y;
  const int wave = tid >> 6, lane = tid & 63;
  const int wm = wave & 1, wn = (wave >> 1) & 1, kw = wave >> 2;
  const int l32 = lane & 31, h32 = lane >> 5;

  f32x16 acc = {0,0,0,0,0,0,0,0,0,0,0,0,0,0,0,0};

  const int sr = tid >> 3, sc = tid & 7;
  const float* hA = h + (size_t)(i0a + sr)*FIN + sc*8;
  const char*  wB = (const char*)wp + ((size_t)(head*12*64 + sr))*128 + sc*16;
  const int aslot = (sc ^ (sr & 7)) << 4;

  float4 ra0 = *(const float4*)(hA);
  float4 ra1 = *(const float4*)(hA + 4);
  float4 ra2 = *(const float4*)(hA + 64);
  float4 ra3 = *(const float4*)(hA + 68);
  u16x8  rb0 = *(const u16x8*)(wB);
  u16x8  rb1 = *(const u16x8*)(wB + 8192);

  for (int it = 0; it < 6; ++it){
    char* Ab = smem + (it & 1)*16384;
    char* Bb = smem + 32768 + (it & 1)*16384;
    u16x8 pk0, pk1;
    pk0[0]=f2bf(ra0.x); pk0[1]=f2bf(ra0.y); pk0[2]=f2bf(ra0.z); pk0[3]=f2bf(ra0.w);
    pk0[4]=f2bf(ra1.x); pk0[5]=f2bf(ra1.y); pk0[6]=f2bf(ra1.z); pk0[7]=f2bf(ra1.w);
    pk1[0]=f2bf(ra2.x); pk1[1]=f2bf(ra2.y); pk1[2]=f2bf(ra2.z); pk1[3]=f2bf(ra2.w);
    pk1[4]=f2bf(ra3.x); pk1[5]=f2bf(ra3.y); pk1[6]=f2bf(ra3.z); pk1[7]=f2bf(ra3.w);
    *(u16x8*)(Ab + sr*256 + aslot)        = pk0;
    *(u16x8*)(Ab + sr*256 + 128 + aslot)  = pk1;
    *(u16x8*)(Bb + sr*256 + sc*16)        = rb0;
    *(u16x8*)(Bb + sr*256 + 128 + sc*16)  = rb1;
    __syncthreads();
    if (it < 5){
      const float* an = hA + (it+1)*128;
      ra0 = *(const float4*)(an);      ra1 = *(const float4*)(an + 4);
      ra2 = *(const float4*)(an + 64); ra3 = *(const float4*)(an + 68);
      const char* bn = wB + (size_t)(2*(it+1))*8192;
      rb0 = *(const u16x8*)(bn);       rb1 = *(const u16x8*)(bn + 8192);
    }
    #pragma unroll
    for (int s = 0; s < 4; ++s){
      const int slot = (((s*2 + h32) ^ (l32 & 7)) << 4);
      bf16x8 av = *(const bf16x8*)(Ab + (wm*32 + l32)*256 + kw*128 + slot);
      bf16x8 bv = *(const bf16x8*)(Bb + (wn*32 + l32)*256 + kw*128 + slot);
      acc = __builtin_amdgcn_mfma_f32_32x32x16_bf16(av, bv, acc, 0, 0, 0);
    }
  }

  if (kw == 1) *(f32x16*)(smem + (size_t)((wave & 3)*64 + lane)*64) = acc;
  __syncthreads();
  if (kw == 0){
    acc += *(const f32x16*)(smem + (size_t)((wave & 3)*64 + lane)*64);
    const float as = a_src[head*64 + wn*32 + l32];
    const float ad = a_dst[head*64 + wn*32 + l32];
    #pragma unroll
    for (int rb = 0; rb < 4; ++rb){
      const int jb = wm*32 + rb*8 + h32*4;
      u16x4 c4;
      #pragma unroll
      for (int q = 0; q < 4; ++q){
        const float v = acc[rb*4 + q];
        c4[q] = f2bf(v);
        const float t = tanhf(v);
        float ps = t*as, pd = t*ad;
        ps += __shfl_xor(ps, 1);  ps += __shfl_xor(ps, 2);  ps += __shfl_xor(ps, 4);
        ps += __shfl_xor(ps, 8);  ps += __shfl_xor(ps, 16);
        pd += __shfl_xor(pd, 1);  pd += __shfl_xor(pd, 2);  pd += __shfl_xor(pd, 4);
        pd += __shfl_xor(pd, 8);  pd += __shfl_xor(pd, 16);
        if (l32 == 0){
          psumS[(jb + q)*2 + wn] = ps;
          psumD[(jb + q)*2 + wn] = pd;
        }
      }
      const int orow = wn*32 + l32;
      const int slot = ((jb >> 3) & 7) ^ (orow & 7);
      *(u16x4*)(Tt + orow*128 + slot*16 + (jb & 7)*2) = c4;
    }
  }
  __syncthreads();

  const int bh = (i0a >> 11)*NHEAD + head;
  {
    // chunk-linear store: thread (o = tid&63, c = tid>>6), un-swizzles Tt
    const int o = tid & 63, c = tid >> 6;
    u16x8 val = *(const u16x8*)(Tt + o*128 + (c ^ (o & 7))*16);
    *(u16x8*)((char*)hpz2 + ((size_t)(bh*256 + (jbase >> 3) + c)*64 + o)*16) = val;
  }
  if (tid < 64){
    float sv = (psumS[tid*2] + psumS[tid*2 + 1]) * LOG2E;   // log2 domain
    float dv = (psumD[tid*2] + psumD[tid*2 + 1]) * LOG2E;
    srcv[(size_t)bh*NSEQ + jbase + tid] = sv;
    dstv[(size_t)bh*NSEQ + jbase + tid] = dv;
    float dmx = dv;
    dmx = fmaxf(dmx, __shfl_xor(dmx, 1));  dmx = fmaxf(dmx, __shfl_xor(dmx, 2));
    dmx = fmaxf(dmx, __shfl_xor(dmx, 4));  dmx = fmaxf(dmx, __shfl_xor(dmx, 8));
    dmx = fmaxf(dmx, __shfl_xor(dmx, 16)); dmx = fmaxf(dmx, __shfl_xor(dmx, 32));
    if (tid == 0) atomicMax(&dmaxe[bh], fenc(dmx));
  }
}

// ---------------------------------------------------------------------------
// Kernel B v2: register-direct P. 512 thr = 8 waves (wm in {0,1} = i-half,
// jw in {0..3} = j-split). Each lane computes its OWN A-frag (row l32, 8 j's)
// via exp2; H-frags from LDS (chunk-linear hpz2, rotation swizzle);
// l via ones-B MFMA. 16 windows of 128 j, dbuf, 1 barrier/window.
// ---------------------------------------------------------------------------
__global__ __launch_bounds__(512, 4) void k_attn(
    const unsigned short* __restrict__ hpz2, const float* __restrict__ srcv,
    const float* __restrict__ dstv, const unsigned* __restrict__ dmaxe,
    const float* __restrict__ bias, float* __restrict__ out)
{
  __shared__ __align__(16) char smem[33792];   // 2x16KB H dbuf (merge overlay) + 1KB Lbuf
  float* Lbuf = (float*)(smem + 32768);        // [8][32]

  const int tid = threadIdx.x;
  const int i0  = blockIdx.x * 64;
  const int bh  = blockIdx.y;
  const int wave = tid >> 6, lane = tid & 63;
  const int wm = wave & 1, jw = wave >> 1;
  const int l32 = lane & 31, h32 = lane >> 5;

  const float s2  = srcv[(size_t)bh*NSEQ + i0 + wm*32 + l32];
  const float dm2 = fdec(dmaxe[bh]);
  float m2 = s2 + dm2; m2 = fmaxf(m2, 0.2f*m2);          // exact row max (log2 dom)
  const float* dst = dstv + (size_t)bh*NSEQ;

  const u16x8* gp = (const u16x8*)((const char*)hpz2 + (size_t)bh*256*64*16);

  bf16x8 ones;
  #pragma unroll
  for (int q = 0; q < 8; ++q) ones[q] = (short)0x3F80;   // bf16 1.0

  f32x16 accO0 = {0,0,0,0,0,0,0,0,0,0,0,0,0,0,0,0};
  f32x16 accO1 = {0,0,0,0,0,0,0,0,0,0,0,0,0,0,0,0};
  f32x16 accL  = {0,0,0,0,0,0,0,0,0,0,0,0,0,0,0,0};

  // prologue: stage window 0 (chunk lc -> LDS slot (Jl, (o+Jl)&63))
  {
    u16x8 r0 = gp[tid], r1 = gp[tid + 512];
    const int J0 = tid >> 6,         o0 = tid & 63;
    const int J1 = (tid + 512) >> 6, o1 = tid & 63;
    *(u16x8*)(smem + (J0*64 + ((o0 + J0) & 63))*16) = r0;
    *(u16x8*)(smem + (J1*64 + ((o1 + J1) & 63))*16) = r1;
  }
  __syncthreads();

  for (int w = 0; w < 16; ++w){
    char* cur = smem + (w & 1)*16384;
    char* nxt = smem + ((w + 1) & 1)*16384;
    u16x8 r0, r1;
    if (w < 15){
      r0 = gp[(w+1)*1024 + tid];
      r1 = gp[(w+1)*1024 + tid + 512];
    }
    #pragma unroll
    for (int stl = 0; stl < 2; ++stl){
      const int Jl = jw*4 + stl*2 + h32;
      const int j0 = (w*16 + Jl)*8;
      float4 d0 = *(const float4*)(dst + j0);
      float4 d1 = *(const float4*)(dst + j0 + 4);
      float e0,e1,e2,e3,e4,e5,e6,e7, x;
      x = s2 + d0.x; x = fmaxf(x, 0.2f*x); e0 = fexp2(x - m2);
      x = s2 + d0.y; x = fmaxf(x, 0.2f*x); e1 = fexp2(x - m2);
      x = s2 + d0.z; x = fmaxf(x, 0.2f*x); e2 = fexp2(x - m2);
      x = s2 + d0.w; x = fmaxf(x, 0.2f*x); e3 = fexp2(x - m2);
      x = s2 + d1.x; x = fmaxf(x, 0.2f*x); e4 = fexp2(x - m2);
      x = s2 + d1.y; x = fmaxf(x, 0.2f*x); e5 = fexp2(x - m2);
      x = s2 + d1.z; x = fmaxf(x, 0.2f*x); e6 = fexp2(x - m2);
      x = s2 + d1.w; x = fmaxf(x, 0.2f*x); e7 = fexp2(x - m2);
      u32x4 pk;
      pk[0] = pkbf(e0, e1); pk[1] = pkbf(e2, e3);
      pk[2] = pkbf(e4, e5); pk[3] = pkbf(e6, e7);
      const bf16x8 pA = __builtin_bit_cast(bf16x8, pk);
      const bf16x8 bv0 = *(const bf16x8*)(cur + (Jl*64 + ((     l32 + Jl) & 63))*16);
      const bf16x8 bv1 = *(const bf16x8*)(cur + (Jl*64 + ((32 + l32 + Jl) & 63))*16);
      accO0 = __builtin_amdgcn_mfma_f32_32x32x16_bf16(pA, bv0, accO0, 0, 0, 0);
      accO1 = __builtin_amdgcn_mfma_f32_32x32x16_bf16(pA, bv1, accO1, 0, 0, 0);
      accL  = __builtin_amdgcn_mfma_f32_32x32x16_bf16(pA, ones, accL, 0, 0, 0);
    }
    if (w < 15){
      const int J0 = tid >> 6,         o0 = tid & 63;
      const int J1 = (tid + 512) >> 6, o1 = tid & 63;
      *(u16x8*)(nxt + (J0*64 + ((o0 + J0) & 63))*16) = r0;
      *(u16x8*)(nxt + (J1*64 + ((o1 + J1) & 63))*16) = r1;
    }
    __syncthreads();
  }

  // l partials: C[m][n] identical over n; lanes l32==0 (h32 = 0/1) hold all 32 rows
  if (l32 == 0){
    #pragma unroll
    for (int reg = 0; reg < 16; ++reg){
      const int m = (reg & 3) + 8*(reg >> 2) + 4*h32;
      Lbuf[(wm*4 + jw)*32 + m] = accL[reg];
    }
  }

  const float4 bia = *(const float4*)(bias + (tid & 15)*4);
  #pragma unroll
  for (int ph = 0; ph < 2; ++ph){
    __syncthreads();
    if (wm == ph){
      float* ob = (float*)smem;            // [jw][m 32][o 64] fp32 = 32 KB
      #pragma unroll
      for (int reg = 0; reg < 16; ++reg){
        const int m = (reg & 3) + 8*(reg >> 2) + 4*h32;
        ob[(jw*32 + m)*64 +      l32] = accO0[reg];
        ob[(jw*32 + m)*64 + 32 + l32] = accO1[reg];
      }
    }
    __syncthreads();
    {
      const int i = tid >> 4, o4 = (tid & 15)*4;
      const float* ob = (const float*)smem;
      float4 v0 = *(const float4*)(ob + (0*32 + i)*64 + o4);
      float4 v1 = *(const float4*)(ob + (1*32 + i)*64 + o4);
      float4 v2 = *(const float4*)(ob + (2*32 + i)*64 + o4);
      float4 v3 = *(const float4*)(ob + (3*32 + i)*64 + o4);
      const float l = Lbuf[(ph*4+0)*32 + i] + Lbuf[(ph*4+1)*32 + i]
                    + Lbuf[(ph*4+2)*32 + i] + Lbuf[(ph*4+3)*32 + i];
      const float r = 1.f / l;             // l >= 1 (exp2(0) term present)
      float4 res;
      res.x = (v0.x + v1.x + v2.x + v3.x)*r + bia.x;
      res.y = (v0.y + v1.y + v2.y + v3.y)*r + bia.y;
      res.z = (v0.z + v1.z + v2.z + v3.z)*r + bia.z;
      res.w = (v0.w + v1.w + v2.w + v3.w)*r + bia.w;
      *(float4*)(out + ((size_t)bh*NSEQ + i0 + ph*32 + i)*64 + o4) = res;
    }
  }
}

// ---------------------------------------------------------------------------
extern "C" void kernel_launch(void* const* d_in, const int* in_sizes, int n_in,
                              void* d_out, int out_size, void* d_ws, size_t ws_size,
                              hipStream_t stream)
{
  const float* h     = (const float*)d_in[0];
  const float* w     = (const float*)d_in[1];
  const float* a_src = (const float*)d_in[2];
  const float* a_dst = (const float*)d_in[3];
  const float* bias  = (const float*)d_in[4];
  float* out = (float*)d_out;

  char* ws = (char*)d_ws;
  unsigned short* hpz2 = (unsigned short*)ws;                           // 4 MB bf16 chunk-linear [16][256][64]
  float* srcv = (float*)(ws + (4u<<20));                                // 128 KB (log2-scaled)
  float* dstv = (float*)(ws + (4u<<20) + (128u<<10));                   // 128 KB (log2-scaled)
  unsigned short* wp = (unsigned short*)(ws + (4u<<20) + (256u<<10));   // 384 KB
  unsigned* dmaxe = (unsigned*)(ws + (4u<<20) + (640u<<10));            // 64 B

  k_prep_w<<<dim3(NHEAD, 12), 256, 0, stream>>>(w, wp, dmaxe);
  k_hprime<<<dim3(NSEQ*BSZ/64, NHEAD), 512, 0, stream>>>(h, wp, a_src, a_dst,
                                                         hpz2, srcv, dstv, dmaxe);
  k_attn<<<dim3(NSEQ/64, BH), 512, 0, stream>>>(hpz2, srcv, dstv, dmaxe, bias, out);
}